// Round 8
// baseline (604.605 us; speedup 1.0000x reference)
//
#include <hip/hip_runtime.h>
#include <math.h>

// Problem constants (from reference): B=4, N=50000, E=800000, D=64
#define NB 4
#define NN 50000
#define NE 800000
#define ND 64
#define ROWB (NB * ND)            // 256 bf16 per node row in (N,B,D)
#define RTOT (NB * NN)            // 200000 rows
#define NBLK ((NN + 255) / 256)   // 196 scan blocks
#define XS_STRIDE 36              // dwords per LDS X row: 32 data + 4 pad (16B-aligned rows)

static const long TOT = (long)NB * NN * ND; // 12,800,000 elements

typedef unsigned int uint_t;

// f32 -> bf16 (round-to-nearest-even)
__device__ __forceinline__ unsigned short f2b(float f) {
    unsigned x = __float_as_uint(f);
    unsigned r = (x + 0x7fffu + ((x >> 16) & 1u)) >> 16;
    return (unsigned short)r;
}
__device__ __forceinline__ float b2f(unsigned short u) {
    return __uint_as_float(((unsigned)u) << 16);
}
__device__ __forceinline__ float4 b2f4(ushort4 u) {
    float4 f;
    f.x = b2f(u.x); f.y = b2f(u.y); f.z = b2f(u.z); f.w = b2f(u.w);
    return f;
}

// ---- count in-degree, 4 edges/thread ---------------------------------------
__global__ __launch_bounds__(256) void count4_kernel(const int* __restrict__ col,
                                                     int* __restrict__ cnt) {
    int i = blockIdx.x * 256 + threadIdx.x;
    if (i >= NE / 4) return;
    int4 c = ((const int4*)col)[i];
    atomicAdd(&cnt[c.x], 1);
    atomicAdd(&cnt[c.y], 1);
    atomicAdd(&cnt[c.z], 1);
    atomicAdd(&cnt[c.w], 1);
}

// ---- per-256-chunk sums + dis = rsqrt(cnt+1) fused -------------------------
__global__ __launch_bounds__(256) void bsumdis_kernel(const int* __restrict__ cnt,
                                                      float* __restrict__ dis,
                                                      int* __restrict__ bsum) {
    int i = blockIdx.x * 256 + threadIdx.x;
    int v = (i < NN) ? cnt[i] : 0;
    if (i < NN) dis[i] = rsqrtf((float)v + 1.0f);
    int s = v;
#pragma unroll
    for (int off = 32; off; off >>= 1) s += __shfl_down(s, off);
    __shared__ int sh[4];
    if ((threadIdx.x & 63) == 0) sh[threadIdx.x >> 6] = s;
    __syncthreads();
    if (threadIdx.x == 0) bsum[blockIdx.x] = sh[0] + sh[1] + sh[2] + sh[3];
}

// ---- exclusive scan of NBLK partials (1 block) -----------------------------
__global__ __launch_bounds__(256) void scanb_kernel(const int* __restrict__ bsum,
                                                    int* __restrict__ boff,
                                                    int* __restrict__ ptr) {
    __shared__ int s[256];
    int t = threadIdx.x;
    int v = (t < NBLK) ? bsum[t] : 0;
    s[t] = v;
    __syncthreads();
    for (int off = 1; off < 256; off <<= 1) {
        int u = (t >= off) ? s[t - off] : 0;
        __syncthreads();
        s[t] += u;
        __syncthreads();
    }
    boff[t] = s[t] - v; // exclusive
    if (t == 255) ptr[NN] = s[255]; // == NE
}

// ---- emit ptr / fill -------------------------------------------------------
__global__ __launch_bounds__(256) void emit_kernel(const int* __restrict__ cnt,
                                                   const int* __restrict__ boff,
                                                   int* __restrict__ ptr,
                                                   int* __restrict__ fill) {
    __shared__ int s[256];
    int t = threadIdx.x;
    int i = blockIdx.x * 256 + t;
    int v = (i < NN) ? cnt[i] : 0;
    s[t] = v;
    __syncthreads();
    for (int off = 1; off < 256; off <<= 1) {
        int u = (t >= off) ? s[t - off] : 0;
        __syncthreads();
        s[t] += u;
        __syncthreads();
    }
    if (i < NN) {
        int ex = boff[blockIdx.x] + s[t] - v;
        ptr[i] = ex;
        fill[i] = ex;
    }
}

// ---- CSR fill, 2 edges/thread ----------------------------------------------
__global__ __launch_bounds__(256) void fill2_kernel(const int* __restrict__ row,
                                                    const int* __restrict__ col,
                                                    int* __restrict__ fill,
                                                    int* __restrict__ srow) {
    int i = blockIdx.x * 256 + threadIdx.x;
    if (i >= NE / 2) return;
    int2 r = ((const int2*)row)[i];
    int2 c = ((const int2*)col)[i];
    int p0 = atomicAdd(&fill[c.x], 1);
    srow[p0] = r.x;
    int p1 = atomicAdd(&fill[c.y], 1);
    srow[p1] = r.y;
}

// ---- GEMM body: xwb[n,b,:] = dis[n] * (x[b,n,:] @ W)  (bf16 out, (N,B,D)) --
// 128-row tile, 256 threads, microtile 8 rows (r = tg + 16*i) x 4 cols.
// Inner loop in 8-k groups: X via ds_read_b128 (8 bf16), W 8x float4.
template <bool INF32>
__device__ __forceinline__ void gemm_body(const void* __restrict__ xin,
                                          const float* __restrict__ W,
                                          const float* __restrict__ dis,
                                          unsigned short* __restrict__ xwb) {
    __shared__ unsigned XsU[128 * XS_STRIDE]; // 18.4 KB
    __shared__ float Ws[4096];                // 16 KB
    const int tid = threadIdx.x;
    const int row0 = blockIdx.x * 128;

    for (int i = tid; i < 4096; i += 256) Ws[i] = W[i];

    if constexpr (INF32) {
        const float* x = (const float*)xin;
#pragma unroll
        for (int j = 0; j < 8; ++j) {
            int c = tid + j * 256;          // 2048 float4-chunks
            int lr = c >> 4;
            int k0 = (c & 15) * 4;
            int R = row0 + lr;
            float4 xv = (R < RTOT) ? *(const float4*)(x + (long)R * ND + k0)
                                   : make_float4(0.f, 0.f, 0.f, 0.f);
            XsU[lr * XS_STRIDE + (k0 >> 1) + 0] =
                (uint_t)f2b(xv.x) | ((uint_t)f2b(xv.y) << 16);
            XsU[lr * XS_STRIDE + (k0 >> 1) + 1] =
                (uint_t)f2b(xv.z) | ((uint_t)f2b(xv.w) << 16);
        }
    } else {
        const uint_t* x = (const uint_t*)xin; // bf16 pairs, 32 dwords/row
#pragma unroll
        for (int j = 0; j < 4; ++j) {
            int cc = tid + j * 256;         // 1024 uint4-chunks
            int lr = cc >> 3;
            int kd = (cc & 7) * 4;
            int R = row0 + lr;
            uint4 u = (R < RTOT) ? *(const uint4*)(x + (long)R * 32 + kd)
                                 : make_uint4(0u, 0u, 0u, 0u);
            *(uint4*)&XsU[lr * XS_STRIDE + kd] = u; // rows 16B-aligned (stride 36)
        }
    }
    __syncthreads();

    const int tc = tid & 15, tg = tid >> 4;
    const int c0 = tc * 4;
    float acc[8][4];
#pragma unroll
    for (int i = 0; i < 8; ++i)
#pragma unroll
        for (int j = 0; j < 4; ++j) acc[i][j] = 0.0f;

#pragma unroll
    for (int g = 0; g < 8; ++g) { // 8 k-values per group
        float4 w[8];
#pragma unroll
        for (int k = 0; k < 8; ++k) w[k] = *(const float4*)&Ws[(8 * g + k) * 64 + c0];
#pragma unroll
        for (int i = 0; i < 8; ++i) {
            uint4 u = *(const uint4*)&XsU[(tg + 16 * i) * XS_STRIDE + g * 4];
            float xk0 = __uint_as_float(u.x << 16);
            float xk1 = __uint_as_float(u.x & 0xffff0000u);
            float xk2 = __uint_as_float(u.y << 16);
            float xk3 = __uint_as_float(u.y & 0xffff0000u);
            float xk4 = __uint_as_float(u.z << 16);
            float xk5 = __uint_as_float(u.z & 0xffff0000u);
            float xk6 = __uint_as_float(u.w << 16);
            float xk7 = __uint_as_float(u.w & 0xffff0000u);
#pragma unroll
            for (int j = 0; j < 4; ++j) {
                float a = acc[i][j];
                a = fmaf(xk0, ((const float*)&w[0])[j], a);
                a = fmaf(xk1, ((const float*)&w[1])[j], a);
                a = fmaf(xk2, ((const float*)&w[2])[j], a);
                a = fmaf(xk3, ((const float*)&w[3])[j], a);
                a = fmaf(xk4, ((const float*)&w[4])[j], a);
                a = fmaf(xk5, ((const float*)&w[5])[j], a);
                a = fmaf(xk6, ((const float*)&w[6])[j], a);
                a = fmaf(xk7, ((const float*)&w[7])[j], a);
                acc[i][j] = a;
            }
        }
    }

#pragma unroll
    for (int i = 0; i < 8; ++i) {
        int R = row0 + tg + 16 * i;
        if (R < RTOT) {
            int b = R / NN;
            int n = R - b * NN;
            float sc = dis[n];
            ushort4 p;
            p.x = f2b(acc[i][0] * sc); p.y = f2b(acc[i][1] * sc);
            p.z = f2b(acc[i][2] * sc); p.w = f2b(acc[i][3] * sc);
            *(ushort4*)(xwb + ((long)n * NB + b) * ND + c0) = p;
        }
    }
}

__global__ __launch_bounds__(256) void gemm_l1_kernel(const float* __restrict__ x,
                                                      const float* __restrict__ W,
                                                      const float* __restrict__ dis,
                                                      unsigned short* __restrict__ xwb) {
    gemm_body<true>(x, W, dis, xwb);
}
__global__ __launch_bounds__(256) void gemm_l2_kernel(const unsigned short* __restrict__ x,
                                                      const float* __restrict__ W,
                                                      const float* __restrict__ dis,
                                                      unsigned short* __restrict__ xwb) {
    gemm_body<false>(x, W, dis, xwb);
}

// ---- fused gather: out = tanh(dis[c]*(sum srcs + self) + bias) -------------
// One wave per target node; pure adds (norm factored out).
// UN = edge-unroll depth (MLP A/B: l1=8, l2=16).
template <bool OUTF32, int UN>
__device__ __forceinline__ void gather_body(const int* __restrict__ ptr,
                                            const int* __restrict__ srow,
                                            const float* __restrict__ dis,
                                            const unsigned short* __restrict__ xwb,
                                            const float* __restrict__ bias,
                                            void* __restrict__ outv) {
    int node = __builtin_amdgcn_readfirstlane(blockIdx.x * 4 + (threadIdx.x >> 6));
    const int lane = threadIdx.x & 63;
    const int b = lane >> 4;
    const int d0 = (lane & 15) * 4;

    // self-loop summand: xwb[node] (already dis[node]-scaled)
    float4 acc = b2f4(*(const ushort4*)(xwb + (long)node * ROWB + lane * 4));

    int e = ptr[node];
    const int eend = ptr[node + 1];
    for (; e + UN - 1 < eend; e += UN) {
        int s[UN];
        float4 v[UN];
#pragma unroll
        for (int j = 0; j < UN; ++j) s[j] = srow[e + j];
#pragma unroll
        for (int j = 0; j < UN; ++j)
            v[j] = b2f4(*(const ushort4*)(xwb + (long)s[j] * ROWB + lane * 4));
#pragma unroll
        for (int j = 0; j < UN; ++j) {
            acc.x += v[j].x; acc.y += v[j].y; acc.z += v[j].z; acc.w += v[j].w;
        }
    }
    for (; e + 3 < eend; e += 4) {
        int s0 = srow[e], s1 = srow[e + 1], s2 = srow[e + 2], s3 = srow[e + 3];
        float4 v0 = b2f4(*(const ushort4*)(xwb + (long)s0 * ROWB + lane * 4));
        float4 v1 = b2f4(*(const ushort4*)(xwb + (long)s1 * ROWB + lane * 4));
        float4 v2 = b2f4(*(const ushort4*)(xwb + (long)s2 * ROWB + lane * 4));
        float4 v3 = b2f4(*(const ushort4*)(xwb + (long)s3 * ROWB + lane * 4));
        acc.x += v0.x + v1.x + v2.x + v3.x;
        acc.y += v0.y + v1.y + v2.y + v3.y;
        acc.z += v0.z + v1.z + v2.z + v3.z;
        acc.w += v0.w + v1.w + v2.w + v3.w;
    }
    for (; e < eend; ++e) {
        int s = srow[e];
        float4 v = b2f4(*(const ushort4*)(xwb + (long)s * ROWB + lane * 4));
        acc.x += v.x; acc.y += v.y; acc.z += v.z; acc.w += v.w;
    }

    float dn = dis[node];
    float4 bv = *(const float4*)(bias + d0);
    acc.x = tanhf(fmaf(acc.x, dn, bv.x));
    acc.y = tanhf(fmaf(acc.y, dn, bv.y));
    acc.z = tanhf(fmaf(acc.z, dn, bv.z));
    acc.w = tanhf(fmaf(acc.w, dn, bv.w));

    const long oidx = ((long)b * NN + node) * ND + d0; // (B,N,D)
    if constexpr (OUTF32) {
        *(float4*)((float*)outv + oidx) = acc;
    } else {
        ushort4 p;
        p.x = f2b(acc.x); p.y = f2b(acc.y); p.z = f2b(acc.z); p.w = f2b(acc.w);
        *(ushort4*)((unsigned short*)outv + oidx) = p;
    }
}

__global__ __launch_bounds__(256) void gather_l1_kernel(const int* __restrict__ ptr,
                                                        const int* __restrict__ srow,
                                                        const float* __restrict__ dis,
                                                        const unsigned short* __restrict__ xwb,
                                                        const float* __restrict__ bias,
                                                        unsigned short* __restrict__ outv) {
    gather_body<false, 8>(ptr, srow, dis, xwb, bias, outv);
}
__global__ __launch_bounds__(256) void gather_l2_kernel(const int* __restrict__ ptr,
                                                        const int* __restrict__ srow,
                                                        const float* __restrict__ dis,
                                                        const unsigned short* __restrict__ xwb,
                                                        const float* __restrict__ bias,
                                                        float* __restrict__ outv) {
    gather_body<true, 16>(ptr, srow, dis, xwb, bias, outv);
}

extern "C" void kernel_launch(void* const* d_in, const int* in_sizes, int n_in,
                              void* d_out, int out_size, void* d_ws, size_t ws_size,
                              hipStream_t stream) {
    // inputs: 0=t, 1=h, 2=edge_index, 3=W1, 4=b1, 5=W2, 6=b2
    const float* h  = (const float*)d_in[1];
    const int*   ei = (const int*)d_in[2];
    const float* W1 = (const float*)d_in[3];
    const float* b1 = (const float*)d_in[4];
    const float* W2 = (const float*)d_in[5];
    const float* b2 = (const float*)d_in[6];
    float* out = (float*)d_out;

    const int* rowp = ei;        // edge_index[0] = sources
    const int* colp = ei + NE;   // edge_index[1] = targets

    // workspace layout
    unsigned short* xwb = (unsigned short*)d_ws;       // TOT bf16 (N,B,D)
    unsigned short* mid = xwb + TOT;                   // TOT bf16 (B,N,D) layer-1 out
    float* dis   = (float*)(mid + TOT);                // NN
    int*   cnt   = (int*)(dis + NN);                   // NN
    int*   ptr   = cnt + NN;                           // NN+1
    int*   fill  = ptr + NN + 1;                       // NN
    int*   srow  = fill + NN;                          // NE
    int*   bsum  = srow + NE;                          // 256
    int*   boff  = bsum + 256;                         // 256

    const int THREADS = 256;
    const int gridC4 = (NE / 4 + THREADS - 1) / THREADS;  // 782
    const int gridF2 = (NE / 2 + THREADS - 1) / THREADS;  // 1563
    const int gridGemm   = (RTOT + 127) / 128;  // 1563
    const int gridGather = NN / 4;              // 12500

    // ---- normalization + CSR build ----
    hipMemsetAsync(cnt, 0, NN * sizeof(int), stream);
    count4_kernel<<<gridC4, THREADS, 0, stream>>>(colp, cnt);
    bsumdis_kernel<<<NBLK, THREADS, 0, stream>>>(cnt, dis, bsum);
    scanb_kernel<<<1, THREADS, 0, stream>>>(bsum, boff, ptr);
    emit_kernel<<<NBLK, THREADS, 0, stream>>>(cnt, boff, ptr, fill);
    fill2_kernel<<<gridF2, THREADS, 0, stream>>>(rowp, colp, fill, srow);

    // ---- layer 1: h (f32) -> mid (bf16) ----
    gemm_l1_kernel<<<gridGemm, THREADS, 0, stream>>>(h, W1, dis, xwb);
    gather_l1_kernel<<<gridGather, THREADS, 0, stream>>>(ptr, srow, dis, xwb, b1, mid);

    // ---- layer 2: mid (bf16) -> out (f32) ----
    gemm_l2_kernel<<<gridGemm, THREADS, 0, stream>>>(mid, W2, dis, xwb);
    gather_l2_kernel<<<gridGather, THREADS, 0, stream>>>(ptr, srow, dis, xwb, b2, out);
}

// Round 9
// 386.471 us; speedup vs baseline: 1.5644x; 1.5644x over previous
//
#include <hip/hip_runtime.h>
#include <math.h>

// Problem constants (from reference): B=4, N=50000, E=800000, D=64
#define NB 4
#define NN 50000
#define NE 800000
#define ND 64
#define ROWB (NB * ND)            // 256 bf16 per node row in (N,B,D)
#define RTOT (NB * NN)            // 200000 rows
#define NBLK ((NN + 255) / 256)   // 196 scan blocks
#define XS_STRIDE 34              // dwords per LDS X row: 32 k-pairs + 2 pad (8B-aligned)

static const long TOT = (long)NB * NN * ND; // 12,800,000 elements

typedef unsigned int uint_t;

// f32 -> bf16 (round-to-nearest-even)
__device__ __forceinline__ unsigned short f2b(float f) {
    unsigned x = __float_as_uint(f);
    unsigned r = (x + 0x7fffu + ((x >> 16) & 1u)) >> 16;
    return (unsigned short)r;
}
__device__ __forceinline__ float b2f(unsigned short u) {
    return __uint_as_float(((unsigned)u) << 16);
}
__device__ __forceinline__ float4 b2f4(ushort4 u) {
    float4 f;
    f.x = b2f(u.x); f.y = b2f(u.y); f.z = b2f(u.z); f.w = b2f(u.w);
    return f;
}

// ---- count in-degree, 4 edges/thread ---------------------------------------
__global__ __launch_bounds__(256) void count4_kernel(const int* __restrict__ col,
                                                     int* __restrict__ cnt) {
    int i = blockIdx.x * 256 + threadIdx.x;
    if (i >= NE / 4) return;
    int4 c = ((const int4*)col)[i];
    atomicAdd(&cnt[c.x], 1);
    atomicAdd(&cnt[c.y], 1);
    atomicAdd(&cnt[c.z], 1);
    atomicAdd(&cnt[c.w], 1);
}

// ---- per-256-chunk sums + dis = rsqrt(cnt+1) fused -------------------------
__global__ __launch_bounds__(256) void bsumdis_kernel(const int* __restrict__ cnt,
                                                      float* __restrict__ dis,
                                                      int* __restrict__ bsum) {
    int i = blockIdx.x * 256 + threadIdx.x;
    int v = (i < NN) ? cnt[i] : 0;
    if (i < NN) dis[i] = rsqrtf((float)v + 1.0f);
    int s = v;
#pragma unroll
    for (int off = 32; off; off >>= 1) s += __shfl_down(s, off);
    __shared__ int sh[4];
    if ((threadIdx.x & 63) == 0) sh[threadIdx.x >> 6] = s;
    __syncthreads();
    if (threadIdx.x == 0) bsum[blockIdx.x] = sh[0] + sh[1] + sh[2] + sh[3];
}

// ---- exclusive scan of NBLK partials (1 block) -----------------------------
__global__ __launch_bounds__(256) void scanb_kernel(const int* __restrict__ bsum,
                                                    int* __restrict__ boff,
                                                    int* __restrict__ ptr) {
    __shared__ int s[256];
    int t = threadIdx.x;
    int v = (t < NBLK) ? bsum[t] : 0;
    s[t] = v;
    __syncthreads();
    for (int off = 1; off < 256; off <<= 1) {
        int u = (t >= off) ? s[t - off] : 0;
        __syncthreads();
        s[t] += u;
        __syncthreads();
    }
    boff[t] = s[t] - v; // exclusive
    if (t == 255) ptr[NN] = s[255]; // == NE
}

// ---- emit ptr / fill -------------------------------------------------------
__global__ __launch_bounds__(256) void emit_kernel(const int* __restrict__ cnt,
                                                   const int* __restrict__ boff,
                                                   int* __restrict__ ptr,
                                                   int* __restrict__ fill) {
    __shared__ int s[256];
    int t = threadIdx.x;
    int i = blockIdx.x * 256 + t;
    int v = (i < NN) ? cnt[i] : 0;
    s[t] = v;
    __syncthreads();
    for (int off = 1; off < 256; off <<= 1) {
        int u = (t >= off) ? s[t - off] : 0;
        __syncthreads();
        s[t] += u;
        __syncthreads();
    }
    if (i < NN) {
        int ex = boff[blockIdx.x] + s[t] - v;
        ptr[i] = ex;
        fill[i] = ex;
    }
}

// ---- CSR fill, 2 edges/thread ----------------------------------------------
__global__ __launch_bounds__(256) void fill2_kernel(const int* __restrict__ row,
                                                    const int* __restrict__ col,
                                                    int* __restrict__ fill,
                                                    int* __restrict__ srow) {
    int i = blockIdx.x * 256 + threadIdx.x;
    if (i >= NE / 2) return;
    int2 r = ((const int2*)row)[i];
    int2 c = ((const int2*)col)[i];
    int p0 = atomicAdd(&fill[c.x], 1);
    srow[p0] = r.x;
    int p1 = atomicAdd(&fill[c.y], 1);
    srow[p1] = r.y;
}

// ---- GEMM body (round-5 known-good): xwb[n,b,:] = dis[n]*(x[b,n,:] @ W) ----
// 128-row tile, 256 threads, microtile 8 rows (r = tg + 16*i) x 4 cols.
// X staged as bf16 pairs in LDS (uint2/b64 reads, conflict-free), W f32 LDS.
template <bool INF32>
__device__ __forceinline__ void gemm_body(const void* __restrict__ xin,
                                          const float* __restrict__ W,
                                          const float* __restrict__ dis,
                                          unsigned short* __restrict__ xwb) {
    __shared__ unsigned XsU[128 * XS_STRIDE]; // 17.4 KB
    __shared__ float Ws[4096];                // 16 KB
    const int tid = threadIdx.x;
    const int row0 = blockIdx.x * 128;

    for (int i = tid; i < 4096; i += 256) Ws[i] = W[i];

    if constexpr (INF32) {
        const float* x = (const float*)xin;
#pragma unroll
        for (int j = 0; j < 8; ++j) {
            int c = tid + j * 256;          // 2048 float4-chunks
            int lr = c >> 4;
            int k0 = (c & 15) * 4;
            int R = row0 + lr;
            float4 xv = (R < RTOT) ? *(const float4*)(x + (long)R * ND + k0)
                                   : make_float4(0.f, 0.f, 0.f, 0.f);
            XsU[lr * XS_STRIDE + (k0 >> 1) + 0] =
                (uint_t)f2b(xv.x) | ((uint_t)f2b(xv.y) << 16);
            XsU[lr * XS_STRIDE + (k0 >> 1) + 1] =
                (uint_t)f2b(xv.z) | ((uint_t)f2b(xv.w) << 16);
        }
    } else {
        const uint_t* x = (const uint_t*)xin; // bf16 pairs, 32 dwords/row
#pragma unroll
        for (int j = 0; j < 4; ++j) {
            int cc = tid + j * 256;         // 1024 uint4-chunks
            int lr = cc >> 3;
            int kd = (cc & 7) * 4;
            int R = row0 + lr;
            uint4 u = (R < RTOT) ? *(const uint4*)(x + (long)R * 32 + kd)
                                 : make_uint4(0u, 0u, 0u, 0u);
            XsU[lr * XS_STRIDE + kd + 0] = u.x;
            XsU[lr * XS_STRIDE + kd + 1] = u.y;
            XsU[lr * XS_STRIDE + kd + 2] = u.z;
            XsU[lr * XS_STRIDE + kd + 3] = u.w;
        }
    }
    __syncthreads();

    const int tc = tid & 15, tg = tid >> 4;
    const int c0 = tc * 4;
    float acc[8][4];
#pragma unroll
    for (int i = 0; i < 8; ++i)
#pragma unroll
        for (int j = 0; j < 4; ++j) acc[i][j] = 0.0f;

#pragma unroll 4
    for (int kk = 0; kk < 16; ++kk) { // 4 k-values per iter
        float4 w0 = *(const float4*)&Ws[(4 * kk + 0) * 64 + c0];
        float4 w1 = *(const float4*)&Ws[(4 * kk + 1) * 64 + c0];
        float4 w2 = *(const float4*)&Ws[(4 * kk + 2) * 64 + c0];
        float4 w3 = *(const float4*)&Ws[(4 * kk + 3) * 64 + c0];
#pragma unroll
        for (int i = 0; i < 8; ++i) {
            uint2 u = *(const uint2*)&XsU[(tg + 16 * i) * XS_STRIDE + 2 * kk];
            float xa = __uint_as_float(u.x << 16);
            float xb = __uint_as_float(u.x & 0xffff0000u);
            float xc = __uint_as_float(u.y << 16);
            float xd = __uint_as_float(u.y & 0xffff0000u);
            acc[i][0] = fmaf(xa, w0.x, acc[i][0]); acc[i][1] = fmaf(xa, w0.y, acc[i][1]);
            acc[i][2] = fmaf(xa, w0.z, acc[i][2]); acc[i][3] = fmaf(xa, w0.w, acc[i][3]);
            acc[i][0] = fmaf(xb, w1.x, acc[i][0]); acc[i][1] = fmaf(xb, w1.y, acc[i][1]);
            acc[i][2] = fmaf(xb, w1.z, acc[i][2]); acc[i][3] = fmaf(xb, w1.w, acc[i][3]);
            acc[i][0] = fmaf(xc, w2.x, acc[i][0]); acc[i][1] = fmaf(xc, w2.y, acc[i][1]);
            acc[i][2] = fmaf(xc, w2.z, acc[i][2]); acc[i][3] = fmaf(xc, w2.w, acc[i][3]);
            acc[i][0] = fmaf(xd, w3.x, acc[i][0]); acc[i][1] = fmaf(xd, w3.y, acc[i][1]);
            acc[i][2] = fmaf(xd, w3.z, acc[i][2]); acc[i][3] = fmaf(xd, w3.w, acc[i][3]);
        }
    }

#pragma unroll
    for (int i = 0; i < 8; ++i) {
        int R = row0 + tg + 16 * i;
        if (R < RTOT) {
            int b = R / NN;
            int n = R - b * NN;
            float sc = dis[n];
            ushort4 p;
            p.x = f2b(acc[i][0] * sc); p.y = f2b(acc[i][1] * sc);
            p.z = f2b(acc[i][2] * sc); p.w = f2b(acc[i][3] * sc);
            *(ushort4*)(xwb + ((long)n * NB + b) * ND + c0) = p;
        }
    }
}

__global__ __launch_bounds__(256, 3) void gemm_l1_kernel(const float* __restrict__ x,
                                                         const float* __restrict__ W,
                                                         const float* __restrict__ dis,
                                                         unsigned short* __restrict__ xwb) {
    gemm_body<true>(x, W, dis, xwb);
}
__global__ __launch_bounds__(256, 3) void gemm_l2_kernel(const unsigned short* __restrict__ x,
                                                         const float* __restrict__ W,
                                                         const float* __restrict__ dis,
                                                         unsigned short* __restrict__ xwb) {
    gemm_body<false>(x, W, dis, xwb);
}

// ---- fused gather: out = tanh(dis[c]*(sum srcs + self) + bias) -------------
// One wave per target node; pure adds (norm factored out).
// UN = edge-unroll depth (MLP A/B: l1=8, l2=16).
template <bool OUTF32, int UN>
__device__ __forceinline__ void gather_body(const int* __restrict__ ptr,
                                            const int* __restrict__ srow,
                                            const float* __restrict__ dis,
                                            const unsigned short* __restrict__ xwb,
                                            const float* __restrict__ bias,
                                            void* __restrict__ outv) {
    int node = __builtin_amdgcn_readfirstlane(blockIdx.x * 4 + (threadIdx.x >> 6));
    const int lane = threadIdx.x & 63;
    const int b = lane >> 4;
    const int d0 = (lane & 15) * 4;

    // self-loop summand: xwb[node] (already dis[node]-scaled)
    float4 acc = b2f4(*(const ushort4*)(xwb + (long)node * ROWB + lane * 4));

    int e = ptr[node];
    const int eend = ptr[node + 1];
    for (; e + UN - 1 < eend; e += UN) {
        int s[UN];
        float4 v[UN];
#pragma unroll
        for (int j = 0; j < UN; ++j) s[j] = srow[e + j];
#pragma unroll
        for (int j = 0; j < UN; ++j)
            v[j] = b2f4(*(const ushort4*)(xwb + (long)s[j] * ROWB + lane * 4));
#pragma unroll
        for (int j = 0; j < UN; ++j) {
            acc.x += v[j].x; acc.y += v[j].y; acc.z += v[j].z; acc.w += v[j].w;
        }
    }
    for (; e + 3 < eend; e += 4) {
        int s0 = srow[e], s1 = srow[e + 1], s2 = srow[e + 2], s3 = srow[e + 3];
        float4 v0 = b2f4(*(const ushort4*)(xwb + (long)s0 * ROWB + lane * 4));
        float4 v1 = b2f4(*(const ushort4*)(xwb + (long)s1 * ROWB + lane * 4));
        float4 v2 = b2f4(*(const ushort4*)(xwb + (long)s2 * ROWB + lane * 4));
        float4 v3 = b2f4(*(const ushort4*)(xwb + (long)s3 * ROWB + lane * 4));
        acc.x += v0.x + v1.x + v2.x + v3.x;
        acc.y += v0.y + v1.y + v2.y + v3.y;
        acc.z += v0.z + v1.z + v2.z + v3.z;
        acc.w += v0.w + v1.w + v2.w + v3.w;
    }
    for (; e < eend; ++e) {
        int s = srow[e];
        float4 v = b2f4(*(const ushort4*)(xwb + (long)s * ROWB + lane * 4));
        acc.x += v.x; acc.y += v.y; acc.z += v.z; acc.w += v.w;
    }

    float dn = dis[node];
    float4 bv = *(const float4*)(bias + d0);
    acc.x = tanhf(fmaf(acc.x, dn, bv.x));
    acc.y = tanhf(fmaf(acc.y, dn, bv.y));
    acc.z = tanhf(fmaf(acc.z, dn, bv.z));
    acc.w = tanhf(fmaf(acc.w, dn, bv.w));

    const long oidx = ((long)b * NN + node) * ND + d0; // (B,N,D)
    if constexpr (OUTF32) {
        *(float4*)((float*)outv + oidx) = acc;
    } else {
        ushort4 p;
        p.x = f2b(acc.x); p.y = f2b(acc.y); p.z = f2b(acc.z); p.w = f2b(acc.w);
        *(ushort4*)((unsigned short*)outv + oidx) = p;
    }
}

__global__ __launch_bounds__(256) void gather_l1_kernel(const int* __restrict__ ptr,
                                                        const int* __restrict__ srow,
                                                        const float* __restrict__ dis,
                                                        const unsigned short* __restrict__ xwb,
                                                        const float* __restrict__ bias,
                                                        unsigned short* __restrict__ outv) {
    gather_body<false, 8>(ptr, srow, dis, xwb, bias, outv);
}
__global__ __launch_bounds__(256) void gather_l2_kernel(const int* __restrict__ ptr,
                                                        const int* __restrict__ srow,
                                                        const float* __restrict__ dis,
                                                        const unsigned short* __restrict__ xwb,
                                                        const float* __restrict__ bias,
                                                        float* __restrict__ outv) {
    gather_body<true, 16>(ptr, srow, dis, xwb, bias, outv);
}

extern "C" void kernel_launch(void* const* d_in, const int* in_sizes, int n_in,
                              void* d_out, int out_size, void* d_ws, size_t ws_size,
                              hipStream_t stream) {
    // inputs: 0=t, 1=h, 2=edge_index, 3=W1, 4=b1, 5=W2, 6=b2
    const float* h  = (const float*)d_in[1];
    const int*   ei = (const int*)d_in[2];
    const float* W1 = (const float*)d_in[3];
    const float* b1 = (const float*)d_in[4];
    const float* W2 = (const float*)d_in[5];
    const float* b2 = (const float*)d_in[6];
    float* out = (float*)d_out;

    const int* rowp = ei;        // edge_index[0] = sources
    const int* colp = ei + NE;   // edge_index[1] = targets

    // workspace layout
    unsigned short* xwb = (unsigned short*)d_ws;       // TOT bf16 (N,B,D)
    unsigned short* mid = xwb + TOT;                   // TOT bf16 (B,N,D) layer-1 out
    float* dis   = (float*)(mid + TOT);                // NN
    int*   cnt   = (int*)(dis + NN);                   // NN
    int*   ptr   = cnt + NN;                           // NN+1
    int*   fill  = ptr + NN + 1;                       // NN
    int*   srow  = fill + NN;                          // NE
    int*   bsum  = srow + NE;                          // 256
    int*   boff  = bsum + 256;                         // 256

    const int THREADS = 256;
    const int gridC4 = (NE / 4 + THREADS - 1) / THREADS;  // 782
    const int gridF2 = (NE / 2 + THREADS - 1) / THREADS;  // 1563
    const int gridGemm   = (RTOT + 127) / 128;  // 1563
    const int gridGather = NN / 4;              // 12500

    // ---- normalization + CSR build ----
    hipMemsetAsync(cnt, 0, NN * sizeof(int), stream);
    count4_kernel<<<gridC4, THREADS, 0, stream>>>(colp, cnt);
    bsumdis_kernel<<<NBLK, THREADS, 0, stream>>>(cnt, dis, bsum);
    scanb_kernel<<<1, THREADS, 0, stream>>>(bsum, boff, ptr);
    emit_kernel<<<NBLK, THREADS, 0, stream>>>(cnt, boff, ptr, fill);
    fill2_kernel<<<gridF2, THREADS, 0, stream>>>(rowp, colp, fill, srow);

    // ---- layer 1: h (f32) -> mid (bf16) ----
    gemm_l1_kernel<<<gridGemm, THREADS, 0, stream>>>(h, W1, dis, xwb);
    gather_l1_kernel<<<gridGather, THREADS, 0, stream>>>(ptr, srow, dis, xwb, b1, mid);

    // ---- layer 2: mid (bf16) -> out (f32) ----
    gemm_l2_kernel<<<gridGemm, THREADS, 0, stream>>>(mid, W2, dis, xwb);
    gather_l2_kernel<<<gridGather, THREADS, 0, stream>>>(ptr, srow, dis, xwb, b2, out);
}